// Round 2
// baseline (817.363 us; speedup 1.0000x reference)
//
#include <hip/hip_runtime.h>

typedef unsigned short ushort_t;
typedef unsigned int uint_t;
typedef short short8 __attribute__((ext_vector_type(8)));
typedef float f32x4 __attribute__((ext_vector_type(4)));
typedef _Float16 half2_t __attribute__((ext_vector_type(2)));

__device__ __forceinline__ ushort_t f2bf(float f) {
  union { float f; uint_t u; } v; v.f = f;
  return (ushort_t)((v.u + 0x7fffu + ((v.u >> 16) & 1u)) >> 16);
}
__device__ __forceinline__ float sigm(float x) { return 1.f / (1.f + __expf(-x)); }
__device__ __forceinline__ float tanh_s(float x) {
  float e = __expf(2.f * fabsf(x));
  float r = 1.f - 2.f / (e + 1.f);
  return copysignf(r, x);
}
__device__ __forceinline__ float dot2h(half2_t a, half2_t b, float c) {
#if __has_builtin(__builtin_amdgcn_fdot2)
  return __builtin_amdgcn_fdot2(a, b, c, false);
#else
  return c + (float)a.x * (float)b.x + (float)a.y * (float)b.y;
#endif
}

#define MFMA16(a, b, c) __builtin_amdgcn_mfma_f32_16x16x32_bf16((a), (b), (c), 0, 0, 0)

// =====================================================================
// Kernel 1: G per row m (640 f32 cols):
//   [ g0+b0 | T1 | T2 | g3+b3 | a4 ]
//   T1 = sigm(gx1+b1+tanh(gt0)), T2 = sigm(gx2+b2+tanh(gt1)),
//   a4 = gx4+b4+gt2,  gt uses clamped Wt[:, :128] = min(Wt,0).
// B-panel: 1024 cols x 64 k, bf16, k XOR-swizzled, 128 KB LDS.
// =====================================================================
__global__ __launch_bounds__(256) void gemm_g(
    const float* __restrict__ x, const float* __restrict__ td,
    const float* __restrict__ wx, const float* __restrict__ wt,
    const float* __restrict__ bias, float* __restrict__ G,
    int t0, int TC, int ltc)
{
  __shared__ ushort_t panel[1024 * 64];
  const int tid = threadIdx.x;
  for (int e = tid; e < 65536; e += 256) {
    int col = e & 1023, k = e >> 10;
    float w;
    if (col < 640) {
      w = wx[k * 640 + col];
    } else {
      int c2 = col - 640;
      w = wt[k * 384 + c2];
      if (c2 < 128) w = fminf(w, 0.f);
    }
    panel[col * 64 + (k ^ ((col & 7) << 3))] = f2bf(w);
  }
  __syncthreads();

  const int wv = tid >> 6, lane = tid & 63;
  const int l15 = lane & 15, lg = lane >> 4;
  const int ntiles = (256 * TC) >> 4;

  for (int T = blockIdx.x * 4 + wv; T < ntiles; T += 1024) {
    // ---- load + convert A fragments (row m, k = lg*8.. and 32+lg*8..) ----
    int m = T * 16 + l15;
    int bb = m >> ltc, tt = m & (TC - 1);
    size_t ro = ((size_t)(bb * 512 + t0 + tt)) * 64 + lg * 8;
    f32x4 xv0 = *(const f32x4*)(x + ro);
    f32x4 xv1 = *(const f32x4*)(x + ro + 4);
    f32x4 xv2 = *(const f32x4*)(x + ro + 32);
    f32x4 xv3 = *(const f32x4*)(x + ro + 36);
    f32x4 tv0 = *(const f32x4*)(td + ro);
    f32x4 tv1 = *(const f32x4*)(td + ro + 4);
    f32x4 tv2 = *(const f32x4*)(td + ro + 32);
    f32x4 tv3 = *(const f32x4*)(td + ro + 36);
    short8 xa0, xa1, ta0, ta1;
#pragma unroll
    for (int j = 0; j < 4; ++j) {
      xa0[j] = (short)f2bf(xv0[j]); xa0[4 + j] = (short)f2bf(xv1[j]);
      xa1[j] = (short)f2bf(xv2[j]); xa1[4 + j] = (short)f2bf(xv3[j]);
      ta0[j] = (short)f2bf(tv0[j]); ta0[4 + j] = (short)f2bf(tv1[j]);
      ta1[j] = (short)f2bf(tv2[j]); ta1[4 + j] = (short)f2bf(tv3[j]);
    }

    for (int n = 0; n < 8; ++n) {
      int colj = n * 16 + l15;  // 0..127 within each 128-col segment
      short8 b0, b1;
      auto ldb = [&](int col) {
        const char* bp = (const char*)panel + col * 128;
        int sw = (col & 7) << 4;
        b0 = *(const short8*)(bp + ((lg * 16) ^ sw));
        b1 = *(const short8*)(bp + ((64 + lg * 16) ^ sw));
      };
      f32x4 g0{}, g1{}, g2{}, g3{}, g4{}, q0{}, q1{}, q2{};
      ldb(colj);        g0 = MFMA16(xa0, b0, g0); g0 = MFMA16(xa1, b1, g0);
      ldb(128 + colj);  g1 = MFMA16(xa0, b0, g1); g1 = MFMA16(xa1, b1, g1);
      ldb(256 + colj);  g2 = MFMA16(xa0, b0, g2); g2 = MFMA16(xa1, b1, g2);
      ldb(384 + colj);  g3 = MFMA16(xa0, b0, g3); g3 = MFMA16(xa1, b1, g3);
      ldb(512 + colj);  g4 = MFMA16(xa0, b0, g4); g4 = MFMA16(xa1, b1, g4);
      ldb(640 + colj);  q0 = MFMA16(ta0, b0, q0); q0 = MFMA16(ta1, b1, q0);
      ldb(768 + colj);  q1 = MFMA16(ta0, b0, q1); q1 = MFMA16(ta1, b1, q1);
      ldb(896 + colj);  q2 = MFMA16(ta0, b0, q2); q2 = MFMA16(ta1, b1, q2);

      float b0f = bias[colj], b1f = bias[128 + colj], b2f = bias[256 + colj];
      float b3f = bias[384 + colj], b4f = bias[512 + colj];
      float* Gr = G + (size_t)(T * 16 + lg * 4) * 640 + colj;
#pragma unroll
      for (int r = 0; r < 4; ++r) {
        float* Gp = Gr + (size_t)r * 640;
        Gp[0]   = g0[r] + b0f;
        Gp[128] = sigm(g1[r] + b1f + tanh_s(q0[r]));
        Gp[256] = sigm(g2[r] + b2f + tanh_s(q1[r]));
        Gp[384] = g3[r] + b3f;
        Gp[512] = g4[r] + b4f + q2[r];
      }
    }
  }
}

// =====================================================================
// Kernel 2: serial scan. 1 block = 1 batch row, 384 threads.
// Thread j holds Wh[:, j] as 64 f16 pairs; per step:
//   xh_j = dot2 over h (broadcast from LDS) -> xh LDS -> gates on
//   threads 0..127 (c in registers), G prefetched one step ahead.
// =====================================================================
__global__ __launch_bounds__(384) void scan_k(
    const float* __restrict__ G, const float* __restrict__ wh,
    float* __restrict__ out, float* __restrict__ sh, float* __restrict__ sc,
    int t0, int t1, int TC)
{
  __shared__ __attribute__((aligned(16))) _Float16 h_lds[128];
  __shared__ float xh_lds[384];
  const int tid = threadIdx.x;
  const int b = blockIdx.x;

  // Wh column `tid` as 64 f16 pairs
  half2_t w2[64];
  {
    const float* wp = wh + tid;
#pragma unroll
    for (int k = 0; k < 64; ++k)
      w2[k] = half2_t{(_Float16)wp[(2 * k) * 384], (_Float16)wp[(2 * k + 1) * 384]};
  }

  float c_last = 0.f, h0v = 0.f;
  if (tid < 128) {
    if (t0 > 0) { h0v = sh[b * 128 + tid]; c_last = sc[b * 128 + tid]; }
    h_lds[tid] = (_Float16)h0v;
  }
  float h_last = h0v;

  const float* Gb = G + (size_t)b * TC * 640;
  float gc[5], gn[5];
  if (tid < 128) {
#pragma unroll
    for (int g = 0; g < 5; ++g) gc[g] = Gb[g * 128 + tid];
  }
  __syncthreads();

  for (int t = t0; t < t1; ++t) {
    int tt = t - t0;
    if (tid < 128) {
      int ttn = (tt + 1 < TC) ? (tt + 1) : tt;
      const float* gp = Gb + (size_t)ttn * 640 + tid;
#pragma unroll
      for (int g = 0; g < 5; ++g) gn[g] = gp[g * 128];
    }

    // ---- dot phase: xh_j = sum_k h_k * Wh[k][j], 4 independent chains ----
    float a0 = 0.f, a1 = 0.f, a2 = 0.f, a3 = 0.f;
    const short8* hv8 = (const short8*)h_lds;
#pragma unroll
    for (int kk = 0; kk < 16; ++kk) {
      union { short8 s; half2_t h[4]; } u; u.s = hv8[kk];
      a0 = dot2h(u.h[0], w2[kk * 4 + 0], a0);
      a1 = dot2h(u.h[1], w2[kk * 4 + 1], a1);
      a2 = dot2h(u.h[2], w2[kk * 4 + 2], a2);
      a3 = dot2h(u.h[3], w2[kk * 4 + 3], a3);
    }
    xh_lds[tid] = (a0 + a1) + (a2 + a3);
    __syncthreads();

    // ---- gate phase on threads 0..127 ----
    if (tid < 128) {
      float xh0 = xh_lds[tid], xh1 = xh_lds[tid + 128], xh2v = xh_lds[tid + 256];
      float i_t = sigm(gc[0] + xh0);
      float it1 = i_t * gc[1];                    // gc[1] = T1 (precomputed sigm)
      float cwa = tanh_s(gc[3] + xh1);
      float ctl = sigm((1.f - it1) * c_last + it1 * cwa);
      float cnw = sigm((1.f - i_t) * c_last + i_t * gc[2] * cwa);  // gc[2] = T2
      float o_t = sigm(gc[4] + xh2v);             // gc[4] = gx4+b4+gt2
      float hn = o_t + tanh_s(ctl);
      out[((size_t)b * 512 + t) * 128 + tid] = hn;
      h_lds[tid] = (_Float16)hn;
      c_last = cnw; h_last = hn;
#pragma unroll
      for (int g = 0; g < 5; ++g) gc[g] = gn[g];
    }
    __syncthreads();
  }

  if (tid < 128) {
    if (t1 == 512) {
      out[(size_t)16777216 + b * 128 + tid] = h_last;            // h_f
      out[(size_t)16777216 + 32768 + b * 128 + tid] = c_last;    // c_f
    } else {
      sh[b * 128 + tid] = h_last;
      sc[b * 128 + tid] = c_last;
    }
  }
}

// =====================================================================
extern "C" void kernel_launch(void* const* d_in, const int* in_sizes, int n_in,
                              void* d_out, int out_size, void* d_ws, size_t ws_size,
                              hipStream_t stream) {
  const float* x    = (const float*)d_in[0];
  const float* td   = (const float*)d_in[1];
  const float* wx   = (const float*)d_in[2];
  const float* wh   = (const float*)d_in[3];
  const float* wt   = (const float*)d_in[4];
  const float* bias = (const float*)d_in[5];
  float* out = (float*)d_out;

  // G chunk must fit d_ws: bytes = 256*TC*640*4 + sh/sc carry (256 KB)
  int TC = 128;
  while (TC > 1 && (size_t)256 * TC * 640 * 4 + 262144 > ws_size) TC >>= 1;
  int ltc = 0; while ((1 << ltc) < TC) ++ltc;

  float* G = (float*)d_ws;
  float* sh = (float*)((char*)d_ws + (size_t)256 * TC * 640 * 4);
  float* sc = sh + 256 * 128;

  for (int t0 = 0; t0 < 512; t0 += TC) {
    gemm_g<<<256, 256, 0, stream>>>(x, td, wx, wt, bias, G, t0, TC, ltc);
    scan_k<<<256, 384, 0, stream>>>(G, wh, out, sh, sc, t0, t0 + TC, TC);
  }
}

// Round 3
// 655.623 us; speedup vs baseline: 1.2467x; 1.2467x over previous
//
#include <hip/hip_runtime.h>

typedef unsigned short ushort_t;
typedef unsigned int uint_t;
typedef short short8 __attribute__((ext_vector_type(8)));
typedef float f32x4 __attribute__((ext_vector_type(4)));
typedef _Float16 half2_t __attribute__((ext_vector_type(2)));

__device__ __forceinline__ ushort_t f2bf(float f) {
  union { float f; uint_t u; } v; v.f = f;
  return (ushort_t)((v.u + 0x7fffu + ((v.u >> 16) & 1u)) >> 16);
}
__device__ __forceinline__ float sigm(float x) { return 1.f / (1.f + __expf(-x)); }
__device__ __forceinline__ float tanh_s(float x) {
  float e = __expf(2.f * fabsf(x));
  float r = 1.f - 2.f / (e + 1.f);
  return copysignf(r, x);
}
__device__ __forceinline__ float dot2h(half2_t a, half2_t b, float c) {
#if __has_builtin(__builtin_amdgcn_fdot2)
  return __builtin_amdgcn_fdot2(a, b, c, false);
#else
  return c + (float)a.x * (float)b.x + (float)a.y * (float)b.y;
#endif
}
__device__ __forceinline__ uint_t cvtpk_bf16(float a, float b) {
  uint_t r;
  asm("v_cvt_pk_bf16_f32 %0, %1, %2" : "=v"(r) : "v"(a), "v"(b));
  return r;
}
// load 8 consecutive f32 and pack to bf16 short8 (A fragment)
__device__ __forceinline__ short8 ld_cvt8(const float* p) {
  f32x4 v0 = *(const f32x4*)p;
  f32x4 v1 = *(const f32x4*)(p + 4);
  union { short8 s; uint_t u[4]; } r;
  r.u[0] = cvtpk_bf16(v0[0], v0[1]);
  r.u[1] = cvtpk_bf16(v0[2], v0[3]);
  r.u[2] = cvtpk_bf16(v1[0], v1[1]);
  r.u[3] = cvtpk_bf16(v1[2], v1[3]);
  return r.s;
}

#define MFMA16(a, b, c) __builtin_amdgcn_mfma_f32_16x16x32_bf16((a), (b), (c), 0, 0, 0)

// =====================================================================
// Kernel 1: fused-gate GEMM, segment-split for occupancy.
// Output G (f16, 640 cols per row):
//   seg0: gx0+b0 | seg1: sigm(gx1+b1+tanh(gt0)) | seg2: sigm(gx2+b2+tanh(gt1))
//   seg3: gx3+b3 | seg4: gx4+b4+gt2        (gt0 uses min(Wt[:,0:128],0))
// Block = 64 rows x 1 segment; panel = 128 or 256 weight cols bf16 (16/32 KB).
// =====================================================================
__global__ __launch_bounds__(256) void gemm_g(
    const float* __restrict__ x, const float* __restrict__ td,
    const float* __restrict__ wx, const float* __restrict__ wt,
    const float* __restrict__ bias, _Float16* __restrict__ G,
    int t0, int TC, int ltc)
{
  __shared__ ushort_t panel[256 * 64];  // [col][k] bf16, k XOR-swizzled
  const int tid = threadIdx.x;
  const int seg = blockIdx.y;
  const bool hasq = (seg == 1) | (seg == 2) | (seg == 4);
  const int wtoff = (seg == 1) ? 0 : (seg == 2) ? 128 : 256;

  if (hasq) {
    for (int e = tid; e < 16384; e += 256) {
      int col = e & 255, k = e >> 8;
      float w;
      if (col < 128) w = wx[k * 640 + seg * 128 + col];
      else {
        w = wt[k * 384 + wtoff + (col - 128)];
        if (seg == 1) w = fminf(w, 0.f);
      }
      panel[col * 64 + (k ^ ((col & 7) << 3))] = f2bf(w);
    }
  } else {
    for (int e = tid; e < 8192; e += 256) {
      int col = e & 127, k = e >> 7;
      panel[col * 64 + (k ^ ((col & 7) << 3))] = f2bf(wx[k * 640 + seg * 128 + col]);
    }
  }
  __syncthreads();

  const int wv = tid >> 6, lane = tid & 63;
  const int l15 = lane & 15, lg = lane >> 4;

  // this wave's 16-row tile (chunk-local rows m0..m0+15)
  const int m0 = blockIdx.x * 64 + wv * 16;
  const int m = m0 + l15;
  const int bb = m >> ltc, tt = m & (TC - 1);
  const size_t ro = ((size_t)(bb * 512 + t0 + tt)) * 64 + lg * 8;

  short8 xa0 = ld_cvt8(x + ro);
  short8 xa1 = ld_cvt8(x + ro + 32);
  short8 ta0{}, ta1{};
  if (hasq) { ta0 = ld_cvt8(td + ro); ta1 = ld_cvt8(td + ro + 32); }

  _Float16* Gw = G + (size_t)(m0 + lg * 4) * 640 + seg * 128;

#pragma unroll
  for (int n = 0; n < 8; ++n) {
    int colj = n * 16 + l15;
    const char* bp = (const char*)panel + colj * 128;
    int sw = (colj & 7) << 4;
    short8 b0 = *(const short8*)(bp + ((lg * 16) ^ sw));
    short8 b1 = *(const short8*)(bp + ((64 + lg * 16) ^ sw));
    f32x4 g{};
    g = MFMA16(xa0, b0, g);
    g = MFMA16(xa1, b1, g);
    f32x4 q{};
    if (hasq) {
      const char* qp = bp + 128 * 128;
      short8 c0 = *(const short8*)(qp + ((lg * 16) ^ sw));
      short8 c1 = *(const short8*)(qp + ((64 + lg * 16) ^ sw));
      q = MFMA16(ta0, c0, q);
      q = MFMA16(ta1, c1, q);
    }
    float bf = bias[seg * 128 + colj];
#pragma unroll
    for (int r = 0; r < 4; ++r) {
      float v;
      if (seg == 1 || seg == 2) v = sigm(g[r] + bf + tanh_s(q[r]));
      else if (seg == 4)        v = g[r] + bf + q[r];
      else                      v = g[r] + bf;
      Gw[(size_t)r * 640 + colj] = (_Float16)v;
    }
  }
}

// =====================================================================
// Kernel 2: serial scan. 1 block = 1 batch row, 768 threads (split-k).
// Thread (j, half) holds Wh[half*64 .. +64, j] as 32 f16 pairs; per step:
//   partial dot over its k-half (h broadcast from LDS), combine in gate
//   phase on threads 0..127 (c in registers), G prefetched 1 step ahead.
// =====================================================================
__global__ __launch_bounds__(768) void scan_k(
    const _Float16* __restrict__ G, const float* __restrict__ wh,
    float* __restrict__ out, float* __restrict__ sh, float* __restrict__ sc,
    int t0, int t1, int TC)
{
  __shared__ __attribute__((aligned(16))) _Float16 h_lds[128];
  __shared__ float xh_lds[768];
  const int tid = threadIdx.x;
  const int b = blockIdx.x;
  const int half = (tid >= 384) ? 1 : 0;
  const int j = tid - half * 384;

  // Wh[half*64 + 2k .. +1][j] as f16 pairs (32 VGPRs)
  half2_t w2[32];
  {
    const float* wp = wh + (size_t)(half * 64) * 384 + j;
#pragma unroll
    for (int k = 0; k < 32; ++k)
      w2[k] = half2_t{(_Float16)wp[(2 * k) * 384], (_Float16)wp[(2 * k + 1) * 384]};
  }

  float c_last = 0.f, h0v = 0.f;
  if (tid < 128) {
    if (t0 > 0) { h0v = sh[b * 128 + tid]; c_last = sc[b * 128 + tid]; }
    h_lds[tid] = (_Float16)h0v;
  }
  float h_last = h0v;

  const _Float16* Gb = G + (size_t)b * TC * 640;
  float gc[5], gn[5];
  if (tid < 128) {
#pragma unroll
    for (int g = 0; g < 5; ++g) gc[g] = (float)Gb[g * 128 + tid];
  }
  __syncthreads();

  for (int t = t0; t < t1; ++t) {
    int tt = t - t0;
    if (tid < 128) {
      int ttn = (tt + 1 < TC) ? (tt + 1) : tt;
      const _Float16* gp = Gb + (size_t)ttn * 640 + tid;
#pragma unroll
      for (int g = 0; g < 5; ++g) gn[g] = (float)gp[g * 128];
    }

    // ---- partial dot over this thread's k-half ----
    float a0 = 0.f, a1 = 0.f, a2 = 0.f, a3 = 0.f;
    const short8* hv8 = ((const short8*)h_lds) + half * 8;
#pragma unroll
    for (int kk = 0; kk < 8; ++kk) {
      union { short8 s; half2_t h[4]; } u; u.s = hv8[kk];
      a0 = dot2h(u.h[0], w2[kk * 4 + 0], a0);
      a1 = dot2h(u.h[1], w2[kk * 4 + 1], a1);
      a2 = dot2h(u.h[2], w2[kk * 4 + 2], a2);
      a3 = dot2h(u.h[3], w2[kk * 4 + 3], a3);
    }
    xh_lds[tid] = (a0 + a1) + (a2 + a3);
    __syncthreads();

    // ---- gate phase on threads 0..127 ----
    if (tid < 128) {
      float xh0 = xh_lds[tid]       + xh_lds[tid + 384];
      float xh1 = xh_lds[tid + 128] + xh_lds[tid + 512];
      float xh2 = xh_lds[tid + 256] + xh_lds[tid + 640];
      float i_t = sigm(gc[0] + xh0);
      float it1 = i_t * gc[1];                     // gc[1] = T1
      float cwa = tanh_s(gc[3] + xh1);
      float ctl = sigm((1.f - it1) * c_last + it1 * cwa);
      float cnw = sigm((1.f - i_t) * c_last + i_t * gc[2] * cwa);  // gc[2] = T2
      float o_t = sigm(gc[4] + xh2);               // gc[4] = gx4+b4+gt2
      float hn = o_t + tanh_s(ctl);
      out[((size_t)b * 512 + t) * 128 + tid] = hn;
      h_lds[tid] = (_Float16)hn;
      c_last = cnw; h_last = hn;
#pragma unroll
      for (int g = 0; g < 5; ++g) gc[g] = gn[g];
    }
    __syncthreads();
  }

  if (tid < 128) {
    if (t1 == 512) {
      out[(size_t)16777216 + b * 128 + tid] = h_last;            // h_f
      out[(size_t)16777216 + 32768 + b * 128 + tid] = c_last;    // c_f
    } else {
      sh[b * 128 + tid] = h_last;
      sc[b * 128 + tid] = c_last;
    }
  }
}

// =====================================================================
extern "C" void kernel_launch(void* const* d_in, const int* in_sizes, int n_in,
                              void* d_out, int out_size, void* d_ws, size_t ws_size,
                              hipStream_t stream) {
  const float* x    = (const float*)d_in[0];
  const float* td   = (const float*)d_in[1];
  const float* wx   = (const float*)d_in[2];
  const float* wh   = (const float*)d_in[3];
  const float* wt   = (const float*)d_in[4];
  const float* bias = (const float*)d_in[5];
  float* out = (float*)d_out;

  // G chunk (f16) must fit d_ws: 256*TC*640*2 bytes + 256KB carry
  int TC = 512;
  while (TC > 8 && (size_t)256 * TC * 640 * 2 + 262144 > ws_size) TC >>= 1;
  int ltc = 0; while ((1 << ltc) < TC) ++ltc;

  _Float16* G = (_Float16*)d_ws;
  float* sh = (float*)((char*)d_ws + (size_t)256 * TC * 640 * 2);
  float* sc = sh + 256 * 128;

  for (int t0 = 0; t0 < 512; t0 += TC) {
    dim3 ggrid(256 * TC / 64, 5);
    gemm_g<<<ggrid, 256, 0, stream>>>(x, td, wx, wt, bias, G, t0, TC, ltc);
    scan_k<<<256, 768, 0, stream>>>(G, wh, out, sh, sc, t0, t0 + TC, TC);
  }
}

// Round 4
// 611.164 us; speedup vs baseline: 1.3374x; 1.0727x over previous
//
#include <hip/hip_runtime.h>

typedef unsigned short ushort_t;
typedef unsigned int uint_t;
typedef short short8 __attribute__((ext_vector_type(8)));
typedef float f32x4 __attribute__((ext_vector_type(4)));
typedef _Float16 half2_t __attribute__((ext_vector_type(2)));

__device__ __forceinline__ ushort_t f2bf(float f) {
  union { float f; uint_t u; } v; v.f = f;
  return (ushort_t)((v.u + 0x7fffu + ((v.u >> 16) & 1u)) >> 16);
}
__device__ __forceinline__ float sigm(float x) { return 1.f / (1.f + __expf(-x)); }
__device__ __forceinline__ float tanh_s(float x) {
  float e = __expf(2.f * fabsf(x));
  float r = 1.f - 2.f / (e + 1.f);
  return copysignf(r, x);
}
__device__ __forceinline__ float dot2h(half2_t a, half2_t b, float c) {
#if __has_builtin(__builtin_amdgcn_fdot2)
  return __builtin_amdgcn_fdot2(a, b, c, false);
#else
  return c + (float)a.x * (float)b.x + (float)a.y * (float)b.y;
#endif
}
__device__ __forceinline__ uint_t cvtpk_bf16(float a, float b) {
  uint_t r;
  asm("v_cvt_pk_bf16_f32 %0, %1, %2" : "=v"(r) : "v"(a), "v"(b));
  return r;
}
__device__ __forceinline__ short8 ld_cvt8(const float* p) {
  f32x4 v0 = *(const f32x4*)p;
  f32x4 v1 = *(const f32x4*)(p + 4);
  union { short8 s; uint_t u[4]; } r;
  r.u[0] = cvtpk_bf16(v0[0], v0[1]);
  r.u[1] = cvtpk_bf16(v0[2], v0[3]);
  r.u[2] = cvtpk_bf16(v1[0], v1[1]);
  r.u[3] = cvtpk_bf16(v1[2], v1[3]);
  return r.s;
}

#define MFMA16(a, b, c) __builtin_amdgcn_mfma_f32_16x16x32_bf16((a), (b), (c), 0, 0, 0)

// =====================================================================
// Kernel 1: fused-gate GEMM, segment-split, panel amortized over RPT=8
// row-tiles per block.  G layout: [chunkrow][j=0..127][6 f16]:
//   slot0: gx0+b0        (i-gate pre-act)
//   slot1: T1 = sigm(gx1+b1+tanh(gt0))   gt0 uses min(Wt[:,0:128],0)
//   slot2: T2 = sigm(gx2+b2+tanh(gt1))
//   slot3: gx3+b3        (cwa pre-act)
//   slot4: gx4+b4+gt2    (o-gate pre-act)   slot5: pad
// =====================================================================
__global__ __launch_bounds__(256) void gemm_g(
    const float* __restrict__ x, const float* __restrict__ td,
    const float* __restrict__ wx, const float* __restrict__ wt,
    const float* __restrict__ bias, _Float16* __restrict__ G,
    int t0, int TC, int ltc)
{
  __shared__ ushort_t panel[256 * 64];  // [col][k] bf16, k XOR-swizzled
  const int tid = threadIdx.x;
  const int seg = blockIdx.y;
  const bool hasq = (seg == 1) | (seg == 2) | (seg == 4);
  const int wtoff = (seg == 1) ? 0 : (seg == 2) ? 128 : 256;

  if (hasq) {
    for (int e = tid; e < 16384; e += 256) {
      int col = e & 255, k = e >> 8;
      float w;
      if (col < 128) w = wx[k * 640 + seg * 128 + col];
      else {
        w = wt[k * 384 + wtoff + (col - 128)];
        if (seg == 1) w = fminf(w, 0.f);
      }
      panel[col * 64 + (k ^ ((col & 7) << 3))] = f2bf(w);
    }
  } else {
    for (int e = tid; e < 8192; e += 256) {
      int col = e & 127, k = e >> 7;
      panel[col * 64 + (k ^ ((col & 7) << 3))] = f2bf(wx[k * 640 + seg * 128 + col]);
    }
  }
  __syncthreads();

  const int wv = tid >> 6, lane = tid & 63;
  const int l15 = lane & 15, lg = lane >> 4;
  const float bf_base = 0.f;

#pragma unroll 1
  for (int it = 0; it < 8; ++it) {
    const int m0 = (blockIdx.x * 8 + it) * 64 + wv * 16;
    const int m = m0 + l15;
    const int bb = m >> ltc, tt = m & (TC - 1);
    const size_t ro = ((size_t)(bb * 512 + t0 + tt)) * 64 + lg * 8;

    short8 xa0 = ld_cvt8(x + ro);
    short8 xa1 = ld_cvt8(x + ro + 32);
    short8 ta0{}, ta1{};
    if (hasq) { ta0 = ld_cvt8(td + ro); ta1 = ld_cvt8(td + ro + 32); }

    _Float16* Gw = G + ((size_t)(m0 + lg * 4) * 128) * 6 + seg;

#pragma unroll
    for (int n = 0; n < 8; ++n) {
      int colj = n * 16 + l15;
      const char* bp = (const char*)panel + colj * 128;
      int sw = (colj & 7) << 4;
      short8 b0 = *(const short8*)(bp + ((lg * 16) ^ sw));
      short8 b1 = *(const short8*)(bp + ((64 + lg * 16) ^ sw));
      f32x4 g{};
      g = MFMA16(xa0, b0, g);
      g = MFMA16(xa1, b1, g);
      f32x4 q{};
      if (hasq) {
        const char* qp = bp + 128 * 128;
        short8 c0 = *(const short8*)(qp + ((lg * 16) ^ sw));
        short8 c1 = *(const short8*)(qp + ((64 + lg * 16) ^ sw));
        q = MFMA16(ta0, c0, q);
        q = MFMA16(ta1, c1, q);
      }
      float bf = bias[seg * 128 + colj] + bf_base;
#pragma unroll
      for (int r = 0; r < 4; ++r) {
        float v;
        if (seg == 1 || seg == 2) v = sigm(g[r] + bf + tanh_s(q[r]));
        else if (seg == 4)        v = g[r] + bf + q[r];
        else                      v = g[r] + bf;
        Gw[(size_t)r * 768 + colj * 6] = (_Float16)v;
      }
    }
  }
}

// =====================================================================
// Kernel 2: serial scan. 1 block = 1 batch row, 768 threads (split-k).
// Raw s_barrier (NO vmcnt drain) + depth-4 register prefetch of G.
// =====================================================================
__global__ __launch_bounds__(768) void scan_k(
    const _Float16* __restrict__ G, const float* __restrict__ wh,
    float* __restrict__ out, float* __restrict__ sh, float* __restrict__ sc,
    int t0, int t1, int TC)
{
  __shared__ __attribute__((aligned(16))) _Float16 h_lds[128];
  __shared__ float xh_lds[768];
  const int tid = threadIdx.x;
  const int b = blockIdx.x;
  const int half = (tid >= 384) ? 1 : 0;
  const int j = tid - half * 384;

  // Wh[half*64 + 2k .. +1][j] as f16 pairs (32 VGPRs)
  half2_t w2[32];
  {
    const float* wp = wh + (size_t)(half * 64) * 384 + j;
#pragma unroll
    for (int k = 0; k < 32; ++k)
      w2[k] = half2_t{(_Float16)wp[(2 * k) * 384], (_Float16)wp[(2 * k + 1) * 384]};
  }

  float c_last = 0.f, h0v = 0.f;
  if (tid < 128) {
    if (t0 > 0) { h0v = sh[b * 128 + tid]; c_last = sc[b * 128 + tid]; }
    h_lds[tid] = (_Float16)h0v;
  }
  float h_last = h0v;

  const _Float16* Gb = G + (size_t)b * TC * 768;   // 128*6 f16 per row
  const uint_t* G32 = (const uint_t*)Gb + tid * 3; // row stride = 384 u32
  float* outp = out + (size_t)b * 65536 + tid;

  uint_t p0[3], p1[3], p2[3], p3[3];
  if (tid < 128) {
    p0[0] = G32[0];        p0[1] = G32[1];        p0[2] = G32[2];
    p1[0] = G32[384];      p1[1] = G32[385];      p1[2] = G32[386];
    p2[0] = G32[768];      p2[1] = G32[769];      p2[2] = G32[770];
    p3[0] = G32[1152];     p3[1] = G32[1153];     p3[2] = G32[1154];
  }
  __syncthreads();

#define SCAN_STEP(P, TABS)                                                   \
  {                                                                          \
    float a0 = 0.f, a1 = 0.f, a2 = 0.f, a3 = 0.f;                            \
    const short8* hv8 = ((const short8*)h_lds) + half * 8;                   \
    _Pragma("unroll")                                                        \
    for (int kk = 0; kk < 8; ++kk) {                                         \
      union { short8 s; half2_t h[4]; } u; u.s = hv8[kk];                    \
      a0 = dot2h(u.h[0], w2[kk * 4 + 0], a0);                                \
      a1 = dot2h(u.h[1], w2[kk * 4 + 1], a1);                                \
      a2 = dot2h(u.h[2], w2[kk * 4 + 2], a2);                                \
      a3 = dot2h(u.h[3], w2[kk * 4 + 3], a3);                                \
    }                                                                        \
    xh_lds[tid] = (a0 + a1) + (a2 + a3);                                     \
    asm volatile("s_waitcnt lgkmcnt(0)" ::: "memory");                       \
    __builtin_amdgcn_s_barrier();                                            \
    if (tid < 128) {                                                         \
      float xh0 = xh_lds[tid] + xh_lds[tid + 384];                           \
      float xh1 = xh_lds[tid + 128] + xh_lds[tid + 512];                     \
      float xh2 = xh_lds[tid + 256] + xh_lds[tid + 640];                     \
      union { uint_t u; _Float16 h[2]; } u0, u1, u2;                         \
      u0.u = P[0]; u1.u = P[1]; u2.u = P[2];                                 \
      float i_t = sigm((float)u0.h[0] + xh0);                                \
      float it1 = i_t * (float)u0.h[1];                                      \
      float cwa = tanh_s((float)u1.h[1] + xh1);                              \
      float ctl = sigm((1.f - it1) * c_last + it1 * cwa);                    \
      float cnw = sigm((1.f - i_t) * c_last + i_t * (float)u1.h[0] * cwa);   \
      float o_t = sigm((float)u2.h[0] + xh2);                                \
      float hn = o_t + tanh_s(ctl);                                          \
      outp[(size_t)(TABS) * 128] = hn;                                       \
      h_lds[tid] = (_Float16)hn;                                             \
      c_last = cnw; h_last = hn;                                             \
      int ldr = (TABS) - t0 + 4; if (ldr > TC - 1) ldr = TC - 1;             \
      const uint_t* gp = G32 + (size_t)ldr * 384;                            \
      P[0] = gp[0]; P[1] = gp[1]; P[2] = gp[2];                              \
    }                                                                        \
    asm volatile("s_waitcnt lgkmcnt(0)" ::: "memory");                       \
    __builtin_amdgcn_s_barrier();                                            \
  }

  for (int t = t0; t < t1; t += 4) {
    SCAN_STEP(p0, t);
    SCAN_STEP(p1, t + 1);
    SCAN_STEP(p2, t + 2);
    SCAN_STEP(p3, t + 3);
  }
#undef SCAN_STEP

  if (tid < 128) {
    if (t1 == 512) {
      out[(size_t)16777216 + b * 128 + tid] = h_last;            // h_f
      out[(size_t)16777216 + 32768 + b * 128 + tid] = c_last;    // c_f
    } else {
      sh[b * 128 + tid] = h_last;
      sc[b * 128 + tid] = c_last;
    }
  }
}

// =====================================================================
extern "C" void kernel_launch(void* const* d_in, const int* in_sizes, int n_in,
                              void* d_out, int out_size, void* d_ws, size_t ws_size,
                              hipStream_t stream) {
  const float* x    = (const float*)d_in[0];
  const float* td   = (const float*)d_in[1];
  const float* wx   = (const float*)d_in[2];
  const float* wh   = (const float*)d_in[3];
  const float* wt   = (const float*)d_in[4];
  const float* bias = (const float*)d_in[5];
  float* out = (float*)d_out;

  // G chunk: 256*TC rows * 128 j * 12 bytes  (+256KB carry)
  int TC = 512;
  while (TC > 8 && (size_t)256 * TC * 128 * 12 + 262144 > ws_size) TC >>= 1;
  int ltc = 0; while ((1 << ltc) < TC) ++ltc;

  _Float16* G = (_Float16*)d_ws;
  float* sh = (float*)((char*)d_ws + (size_t)256 * TC * 128 * 12);
  float* sc = sh + 256 * 128;

  for (int t0 = 0; t0 < 512; t0 += TC) {
    dim3 ggrid((256 * TC / 64) / 8, 5);
    gemm_g<<<ggrid, 256, 0, stream>>>(x, td, wx, wt, bias, G, t0, TC, ltc);
    scan_k<<<256, 768, 0, stream>>>(G, wh, out, sh, sc, t0, t0 + TC, TC);
  }
}